// Round 8
// baseline (179.749 us; speedup 1.0000x reference)
//
#include <hip/hip_runtime.h>

// WaveConv3d, reduced form:
//   s_k  = signed 4x4x4 block-reduce of x  (8 subbands, 16^3, per (b,c))
//   ih   = sparse 3D DFT of s_k (6x6x3 freqs)
//   oh   = per-frequency 64->64 channel mix  (per b)
//   out  = x - mean_{2x2x2}(x) + (1/8) sum_k sign_k(cell) * idft(oh_k)
// Channel mix couples only within one batch b -> tile the whole pipeline
// over b (x[b] = 64 MB, LLC-resident) and software-pipeline across 6
// launches of one heterogeneous kernel:
//   L0: KA(0)+wtr | L1: KA(1)+mix(0) | L2: KB(0)+mix(1)+KA(2)
//   L3: KB(1)+mix(2)+KA(3) | L4: KB(2)+mix(3) | L5: KB(3)
// KB(b) re-reads x[b] ~2 launches after KA(b) -> LLC hit. out stores NT,
// w-path NT+bf16 (no LLC pollution).

typedef float f32x4 __attribute__((ext_vector_type(4)));

__device__ __forceinline__ unsigned short f2bf(float v) {
  unsigned u = __float_as_uint(v);
  u = (u + 0x7FFFu + ((u >> 16) & 1u)) >> 16;  // RNE
  return (unsigned short)u;
}
__device__ __forceinline__ float bf2f(unsigned short b) {
  return __uint_as_float(((unsigned)b) << 16);
}

__constant__ float C16c[16] = {
  1.0f, 0.92387953251128675f, 0.70710678118654752f, 0.38268343236508977f,
  0.0f, -0.38268343236508977f, -0.70710678118654752f, -0.92387953251128675f,
  -1.0f, -0.92387953251128675f, -0.70710678118654752f, -0.38268343236508977f,
  0.0f, 0.38268343236508977f, 0.70710678118654752f, 0.92387953251128675f
};
__constant__ float S16c[16] = {
  0.0f, 0.38268343236508977f, 0.70710678118654752f, 0.92387953251128675f,
  1.0f, 0.92387953251128675f, 0.70710678118654752f, 0.38268343236508977f,
  0.0f, -0.38268343236508977f, -0.70710678118654752f, -0.92387953251128675f,
  -1.0f, -0.92387953251128675f, -0.70710678118654752f, -0.38268343236508977f
};
__constant__ int KYv[6] = {0, 1, 2, 13, 14, 15};

// ---------------------------------------------------------------------------
// KA: fused analyze + z-DFT + y-DFT for batch b. idx = (c 0..63, px 0..15).
// g2 layout: [b][row 144][px 16][c 64].
__device__ __forceinline__ void role_ka(unsigned char* smem, unsigned idx, int b,
                                        const float* __restrict__ x,
                                        float2* __restrict__ g2) {
  float* sm = (float*)smem;                 // [8][16][17] floats (8704 B)
  float2* fz = (float2*)(smem + 8704);      // [8][3][17] f2    (3264 B)
  unsigned tid = threadIdx.x;
  unsigned px = idx & 15u;
  unsigned c = idx >> 4;
  unsigned bc = (unsigned)b * 64u + c;
  const f32x4* xp4 = (const f32x4*)(x + ((size_t)bc << 18)) + (size_t)px * 4096u;
  unsigned z4 = tid & 15u;
#pragma unroll
  for (int q = 0; q < 4; q++) {
    float a00 = 0.f, a01 = 0.f, a10 = 0.f, a11 = 0.f;  // [dx][zhalf]
#pragma unroll
    for (int i = 0; i < 4; i++) {
      f32x4 v = xp4[i * 1024 + q * 256 + tid];
      float h0 = v.x + v.y, h1 = v.z + v.w;
      a00 += h0; a01 += h1;
      if (i < 2) { a10 += h0; a11 += h1; } else { a10 -= h0; a11 -= h1; }
    }
    float p00 = a00 + __shfl_xor(a00, 16);
    float p01 = a01 + __shfl_xor(a01, 16);
    float p10 = a10 + __shfl_xor(a10, 16);
    float p11 = a11 + __shfl_xor(a11, 16);
    float q00 = __shfl_xor(p00, 32), q01 = __shfl_xor(p01, 32);
    float q10 = __shfl_xor(p10, 32), q11 = __shfl_xor(p11, 32);
    bool hi = (tid >> 5) & 1u;
    float ya0 = p00 + q00, yd0 = hi ? (q00 - p00) : (p00 - q00);
    float ya1 = p01 + q01, yd1 = hi ? (q01 - p01) : (p01 - q01);
    float za0 = p10 + q10, zd0 = hi ? (q10 - p10) : (p10 - q10);
    float za1 = p11 + q11, zd1 = hi ? (q11 - p11) : (p11 - q11);
    if (((tid >> 4) & 3u) == 0u) {
      unsigned py = q * 4 + (tid >> 6);
      float* smp = sm + py * 17u + z4;
      smp[0 * 272] = (ya0 + ya1) * 0.125f;   // k=000
      smp[1 * 272] = (ya0 - ya1) * 0.125f;   // 001
      smp[2 * 272] = (yd0 + yd1) * 0.125f;   // 010
      smp[3 * 272] = (yd0 - yd1) * 0.125f;   // 011
      smp[4 * 272] = (za0 + za1) * 0.125f;   // 100
      smp[5 * 272] = (za0 - za1) * 0.125f;   // 101
      smp[6 * 272] = (zd0 + zd1) * 0.125f;   // 110
      smp[7 * 272] = (zd0 - zd1) * 0.125f;   // 111
    }
  }
  __syncthreads();
  if (tid < 128u) {  // z-DFT
    unsigned k = tid >> 4, y = tid & 15u;
    const float* row = sm + k * 272u + y * 17u;
#pragma unroll
    for (int kz = 0; kz < 3; kz++) {
      float re = 0.f, im = 0.f;
#pragma unroll
      for (int nz = 0; nz < 16; nz++) {
        float vv = row[nz];
        int t16 = (kz * nz) & 15;
        re += vv * C16c[t16];
        im -= vv * S16c[t16];
      }
      fz[k * 51u + kz * 17u + y] = make_float2(re, im);
    }
  }
  __syncthreads();
  if (tid < 144u) {  // y-DFT -> g2[b][row][px][c]
    unsigned k = tid / 18u, r = tid - k * 18u;
    unsigned kyi = r / 3u, kz = r - kyi * 3u;
    int ky = KYv[kyi];
    float re = 0.f, im = 0.f;
#pragma unroll
    for (int ny = 0; ny < 16; ny++) {
      float2 vv = fz[k * 51u + kz * 17u + ny];
      int t16 = (ky * ny) & 15;
      float cc = C16c[t16], sn = S16c[t16];
      re += vv.x * cc + vv.y * sn;
      im += vv.y * cc - vv.x * sn;
    }
    g2[(((size_t)b * 144u + tid) * 16u + px) * 64u + c] = make_float2(re, im);
  }
}

// ---------------------------------------------------------------------------
// mix: x-DFT + channel mix for batch b. idx = (kc, f).
__device__ __forceinline__ void role_mix(unsigned char* smem, unsigned idx, int b,
                                         const unsigned* __restrict__ wtu,
                                         const float2* __restrict__ g2,
                                         float2* __restrict__ oh2) {
  float2* inl = (float2*)smem;             // [64]
  float2* part = (float2*)(smem + 512);    // [4][64]
  unsigned tid = threadIdx.x;
  unsigned f = idx % 27u;
  unsigned kc = idx / 27u;
  unsigned k = kc >> 2, corner = kc & 3u;
  unsigned kz = f % 3u, kyl = (f / 3u) % 3u, kxl = f / 9u;
  unsigned kxi = kxl + 3u * (corner & 1u);
  unsigned kyi = kyl + 3u * (corner >> 1);
  unsigned fg = kxi * 18u + kyi * 3u + kz;
  unsigned row = k * 18u + kyi * 3u + kz;
  if (tid < 64u) {  // Phase A: x-DFT for channel c = tid
    const float2* gp = g2 + (((size_t)b * 144u + row) * 16u) * 64u + tid;
    int kx = KYv[kxi];
    float re = 0.f, im = 0.f;
#pragma unroll
    for (int nx = 0; nx < 16; nx++) {
      float2 vv = gp[nx * 64];
      int t16 = (kx * nx) & 15;
      float cc = C16c[t16], sn = S16c[t16];
      re += vv.x * cc + vv.y * sn;
      im += vv.y * cc - vv.x * sn;
    }
    inl[tid] = make_float2(re, im);
  }
  __syncthreads();
  unsigned q = tid >> 6, o = tid & 63u;
  const unsigned* wp = wtu + ((size_t)kc * 27u + f) * 4096u + o;
  float2 acc = make_float2(0.f, 0.f);
#pragma unroll 16
  for (unsigned i = q * 16u; i < q * 16u + 16u; i++) {
    float2 a = inl[i];
    unsigned pk = __builtin_nontemporal_load(wp + (size_t)i * 64u);
    float wr = bf2f((unsigned short)(pk & 0xFFFFu));
    float wi = bf2f((unsigned short)(pk >> 16));
    acc.x += a.x * wr - a.y * wi;
    acc.y += a.x * wi + a.y * wr;
  }
  part[q * 64u + o] = acc;
  __syncthreads();
  if (tid < 64u) {
    float2 r = part[tid];
#pragma unroll
    for (int qq = 1; qq < 4; qq++) {
      float2 p = part[qq * 64u + tid];
      r.x += p.x; r.y += p.y;
    }
    oh2[((size_t)b * 64u + tid) * 864u + k * 108u + fg] = r;
  }
}

// ---------------------------------------------------------------------------
// KB: inverse DFT + synthesis for batch b. idx = (oo 0..63, sp 0..7).
__device__ __forceinline__ void role_kb(unsigned char* smem, unsigned idx, int b,
                                        const float2* __restrict__ oh2,
                                        const float* __restrict__ x,
                                        float* __restrict__ out) {
  float2* hh = (float2*)smem;              // [864]
  float2* gx = (float2*)(smem + 6912);     // [2][8][18]
  float2* uu = (float2*)(smem + 9216);     // [2][8][3][16]
  float* W = (float*)(smem + 15360);       // [2][8][16][16]
  unsigned tid = threadIdx.x;
  unsigned sp = idx & 7u;
  unsigned bo = ((unsigned)b << 6) + (idx >> 3);
  for (unsigned i = tid; i < 864u; i += 256u)
    hh[i] = oh2[(size_t)bo * 864u + i];
  __syncthreads();
  for (unsigned i = tid; i < 288u; i += 256u) {  // x-inverse (both slabs)
    unsigned sl = i / 144u, j = i - sl * 144u;
    unsigned k = j / 18u, r = j - k * 18u;
    unsigned nx = sp * 2u + sl;
    float re = 0.f, im = 0.f;
#pragma unroll
    for (int kxi = 0; kxi < 6; kxi++) {
      float2 v = hh[k * 108u + kxi * 18 + r];
      int t16 = (KYv[kxi] * (int)nx) & 15;
      float cc = C16c[t16], sn = S16c[t16];
      re += v.x * cc - v.y * sn;
      im += v.x * sn + v.y * cc;
    }
    gx[(sl * 8u + k) * 18u + r] = make_float2(re, im);
  }
  __syncthreads();
  for (unsigned i = tid; i < 768u; i += 256u) {  // y-inverse
    unsigned sl = i / 384u, j = i - sl * 384u;
    unsigned k = j / 48u, rem = j - k * 48u;
    unsigned kz = rem >> 4, ny = rem & 15u;
    float re = 0.f, im = 0.f;
#pragma unroll
    for (int kyi = 0; kyi < 6; kyi++) {
      float2 v = gx[(sl * 8u + k) * 18u + kyi * 3 + kz];
      int t16 = (KYv[kyi] * (int)ny) & 15;
      float cc = C16c[t16], sn = S16c[t16];
      re += v.x * cc - v.y * sn;
      im += v.x * sn + v.y * cc;
    }
    uu[((sl * 8u + k) * 3u + kz) * 16u + ny] = make_float2(re, im);
  }
  __syncthreads();
  for (unsigned i = tid; i < 512u; i += 256u) {  // z-inverse + Hadamard
    unsigned sl = i >> 8, ny = (i >> 4) & 15u, nz = i & 15u;
    float c1 = C16c[nz], s1 = S16c[nz];
    int t2 = (2 * nz) & 15;
    float c2 = C16c[t2], s2 = S16c[t2];
    float val[8];
#pragma unroll
    for (int k = 0; k < 8; k++) {
      float2 u0 = uu[((sl * 8u + k) * 3u + 0) * 16u + ny];
      float2 u1 = uu[((sl * 8u + k) * 3u + 1) * 16u + ny];
      float2 u2 = uu[((sl * 8u + k) * 3u + 2) * 16u + ny];
      val[k] = (u0.x + 2.f * (u1.x * c1 - u1.y * s1) + 2.f * (u2.x * c2 - u2.y * s2)) * (1.f / 4096.f);
    }
#pragma unroll
    for (int st = 1; st < 8; st <<= 1)
#pragma unroll
      for (int i2 = 0; i2 < 8; i2++)
        if (!(i2 & st)) {
          float a = val[i2], bb = val[i2 | st];
          val[i2] = a + bb;
          val[i2 | st] = a - bb;
        }
#pragma unroll
    for (int m = 0; m < 8; m++) W[((sl * 8u + m) * 16u + ny) * 16u + nz] = val[m];
  }
  __syncthreads();
  unsigned w = tid >> 6, l = tid & 63u;
  unsigned z4 = l & 15u, y2 = l >> 4;
  unsigned mmy = ((y2 >> 1) & 1u) << 1;
  const float* xp = x + ((size_t)bo << 18);
  float* op = out + ((size_t)bo << 18);
#pragma unroll
  for (unsigned sl = 0; sl < 2u; ++sl) {
#pragma unroll
    for (unsigned r2 = 0; r2 < 8u; ++r2) {
      unsigned xp2 = r2 & 1u, yg = r2 >> 1;
      unsigned X0 = ((sp * 2u + sl) << 2) + (xp2 << 1);
      unsigned Y = (yg << 4) + (w << 2) + y2;
      size_t off = ((size_t)X0 << 12) + (Y << 6) + (z4 << 2);
      f32x4 v0 = *(const f32x4*)(xp + off);
      f32x4 v1 = *(const f32x4*)(xp + off + 4096u);
      float h0 = v0.x + v0.y + v1.x + v1.y;
      float h1 = v0.z + v0.w + v1.z + v1.w;
      float m0 = (h0 + __shfl_xor(h0, 16)) * 0.125f;
      float m1 = (h1 + __shfl_xor(h1, 16)) * 0.125f;
      unsigned ny = (yg << 2) + w;
      unsigned mm = (xp2 << 2) | mmy;
      float c0 = 0.125f * W[((sl * 8u + mm) * 16u + ny) * 16u + z4] - m0;
      float c1 = 0.125f * W[((sl * 8u + (mm | 1u)) * 16u + ny) * 16u + z4] - m1;
      v0.x += c0; v0.y += c0; v0.z += c1; v0.w += c1;
      v1.x += c0; v1.y += c0; v1.z += c1; v1.w += c1;
      __builtin_nontemporal_store(v0, (f32x4*)(op + off));
      __builtin_nontemporal_store(v1, (f32x4*)(op + off + 4096u));
    }
  }
}

// ---------------------------------------------------------------------------
// wtr: weight transpose -> bf16-packed wtu[kc][f][i][o], NT both ways.
__device__ __forceinline__ void role_wtr(unsigned char* smem, unsigned idx,
                                         const float2* __restrict__ w2,
                                         unsigned* __restrict__ wtu) {
  f32x4* lw4 = (f32x4*)smem;
  float2* lw2 = (float2*)smem;
  unsigned tid = threadIdx.x;
  unsigned kc = idx >> 6, i = idx & 63u;
  const f32x4* src = (const f32x4*)(w2 + ((size_t)kc * 64u + i) * 1728u);
  for (unsigned t = tid; t < 864u; t += 256u)
    lw4[t] = __builtin_nontemporal_load(src + t);
  __syncthreads();
  unsigned* dst = wtu + (size_t)kc * 110592u + (size_t)i * 64u;
  for (unsigned t = tid; t < 1728u; t += 256u) {
    unsigned f = t >> 6, o = t & 63u;
    float2 v = lw2[o * 27u + f];
    unsigned pk = ((unsigned)f2bf(v.y) << 16) | (unsigned)f2bf(v.x);
    __builtin_nontemporal_store(pk, dst + (size_t)f * 4096u + o);
  }
}

// ---------------------------------------------------------------------------
__global__ __launch_bounds__(256) void k_super(
    const float* __restrict__ x, const float2* __restrict__ w2,
    float2* __restrict__ g2, unsigned* __restrict__ wtu,
    float2* __restrict__ oh2, float* __restrict__ out,
    int nKB, int bKB, int nMix, int bMix, int nKA, int bKA) {
  __shared__ __align__(16) unsigned char smem[31744];
  unsigned bid = blockIdx.x;
  if ((int)bid < nKB) { role_kb(smem, bid, bKB, oh2, x, out); return; }
  bid -= (unsigned)nKB;
  if ((int)bid < nMix) { role_mix(smem, bid, bMix, wtu, g2, oh2); return; }
  bid -= (unsigned)nMix;
  if ((int)bid < nKA) { role_ka(smem, bid, bKA, x, g2); return; }
  bid -= (unsigned)nKA;
  role_wtr(smem, bid, w2, wtu);
}

extern "C" void kernel_launch(void* const* d_in, const int* in_sizes, int n_in,
                              void* d_out, int out_size, void* d_ws, size_t ws_size,
                              hipStream_t stream) {
  const float* x = (const float*)d_in[0];
  const float2* w2 = (const float2*)d_in[1];
  float* out = (float*)d_out;

  const size_t G_B = 4ull * 144 * 16 * 64 * 8;   // 4.72 MB
  const size_t WT_B = 32ull * 27 * 4096 * 4;     // 14.2 MB
  const size_t OH_B = 256ull * 864 * 8;          // 1.77 MB

  float2 *g2, *oh2;
  unsigned* wtu;
  char* ws = (char*)d_ws;
  if (ws_size >= G_B + WT_B + OH_B) {
    g2 = (float2*)ws;
    wtu = (unsigned*)(ws + G_B);
    oh2 = (float2*)(ws + G_B + WT_B);
  } else {
    // oh2 must survive to L5 -> ws (needs 1.77 MB). g2/wtu live at the TAIL
    // of d_out (inside out[b=3]): their last reader is mix(3) at L4; KB(3)
    // overwrites that region at L5 when they are dead.
    oh2 = (float2*)ws;
    char* tail = (char*)d_out + (size_t)out_size * 4 - (G_B + WT_B);
    g2 = (float2*)tail;
    wtu = (unsigned*)(tail + G_B);
  }

  const int nKA = 1024, nMix = 864, nKB = 512, nWtr = 2048;
  // L0: KA(0) + wtr
  k_super<<<nKA + nWtr, 256, 0, stream>>>(x, w2, g2, wtu, oh2, out, 0, 0, 0, 0, nKA, 0);
  // L1: mix(0) + KA(1)
  k_super<<<nMix + nKA, 256, 0, stream>>>(x, w2, g2, wtu, oh2, out, 0, 0, nMix, 0, nKA, 1);
  // L2: KB(0) + mix(1) + KA(2)
  k_super<<<nKB + nMix + nKA, 256, 0, stream>>>(x, w2, g2, wtu, oh2, out, nKB, 0, nMix, 1, nKA, 2);
  // L3: KB(1) + mix(2) + KA(3)
  k_super<<<nKB + nMix + nKA, 256, 0, stream>>>(x, w2, g2, wtu, oh2, out, nKB, 1, nMix, 2, nKA, 3);
  // L4: KB(2) + mix(3)
  k_super<<<nKB + nMix, 256, 0, stream>>>(x, w2, g2, wtu, oh2, out, nKB, 2, nMix, 3, 0, 0);
  // L5: KB(3)
  k_super<<<nKB, 256, 0, stream>>>(x, w2, g2, wtu, oh2, out, nKB, 3, 0, 0, 0, 0);
}

// Round 9
// 154.929 us; speedup vs baseline: 1.1602x; 1.1602x over previous
//
#include <hip/hip_runtime.h>

// WaveConv3d, reduced form:
//   s_k  = signed 4x4x4 block-reduce of x  (8 subbands, 16^3 per (b,c))
//   ih   = sparse 3D DFT of s_k (6x6x3 freqs)
//   oh   = per-frequency 64->64 channel mix
//   out  = x - mean_{2x2x2}(x) + (1/8) sum_k sign_k(cell) * idft(oh_k)
// K1 = analyze + z/y-DFT -> g2.  K2 = per-(kc,o-block) WG: in-LDS x-DFT of
// its corner's 27 freqs, then GEMM over i reading w DIRECTLY (original
// layout, 1728B-contiguous (8o x 27f) tiles per i, NT, read exactly once —
// no transpose, no wt/ih intermediates).  K3 = inverse DFT + synthesis
// (normal x loads, reversed order for LLC reuse of K1's tail; NT out).

typedef float f32x4 __attribute__((ext_vector_type(4)));

__constant__ float C16c[16] = {
  1.0f, 0.92387953251128675f, 0.70710678118654752f, 0.38268343236508977f,
  0.0f, -0.38268343236508977f, -0.70710678118654752f, -0.92387953251128675f,
  -1.0f, -0.92387953251128675f, -0.70710678118654752f, -0.38268343236508977f,
  0.0f, 0.38268343236508977f, 0.70710678118654752f, 0.92387953251128675f
};
__constant__ float S16c[16] = {
  0.0f, 0.38268343236508977f, 0.70710678118654752f, 0.92387953251128675f,
  1.0f, 0.92387953251128675f, 0.70710678118654752f, 0.38268343236508977f,
  0.0f, -0.38268343236508977f, -0.70710678118654752f, -0.92387953251128675f,
  -1.0f, -0.92387953251128675f, -0.70710678118654752f, -0.38268343236508977f
};
__constant__ int KYv[6] = {0, 1, 2, 13, 14, 15};

// ---------------------------------------------------------------------------
// K1: fused analyze + z-DFT + y-DFT. WG = (bc, px).
// g2 layout: [b][row 144][px 16][c 64], row = k*18 + kyi*3 + kz.
__global__ __launch_bounds__(256) void k1_front(const float* __restrict__ x,
                                                float2* __restrict__ g2) {
  __shared__ float sm[8 * 16 * 17 + 8];            // [k][py][pz(17)]
  __shared__ float2 fz[8 * 3 * 17];                // [k][kz][ny(17)]
  unsigned tid = threadIdx.x;
  unsigned px = blockIdx.x & 15u;
  unsigned bc = blockIdx.x >> 4;
  unsigned c = bc & 63u, b = bc >> 6;
  const f32x4* xp4 = (const f32x4*)(x + ((size_t)bc << 18)) + (size_t)px * 4096u;
  unsigned z4 = tid & 15u;
#pragma unroll
  for (int q = 0; q < 4; q++) {
    float a00 = 0.f, a01 = 0.f, a10 = 0.f, a11 = 0.f;  // [dx][zhalf]
#pragma unroll
    for (int i = 0; i < 4; i++) {
      f32x4 v = xp4[i * 1024 + q * 256 + tid];
      float h0 = v.x + v.y, h1 = v.z + v.w;
      a00 += h0; a01 += h1;
      if (i < 2) { a10 += h0; a11 += h1; } else { a10 -= h0; a11 -= h1; }
    }
    float p00 = a00 + __shfl_xor(a00, 16);
    float p01 = a01 + __shfl_xor(a01, 16);
    float p10 = a10 + __shfl_xor(a10, 16);
    float p11 = a11 + __shfl_xor(a11, 16);
    float q00 = __shfl_xor(p00, 32), q01 = __shfl_xor(p01, 32);
    float q10 = __shfl_xor(p10, 32), q11 = __shfl_xor(p11, 32);
    bool hi = (tid >> 5) & 1u;
    float ya0 = p00 + q00, yd0 = hi ? (q00 - p00) : (p00 - q00);
    float ya1 = p01 + q01, yd1 = hi ? (q01 - p01) : (p01 - q01);
    float za0 = p10 + q10, zd0 = hi ? (q10 - p10) : (p10 - q10);
    float za1 = p11 + q11, zd1 = hi ? (q11 - p11) : (p11 - q11);
    if (((tid >> 4) & 3u) == 0u) {
      unsigned py = q * 4 + (tid >> 6);
      float* smp = sm + py * 17u + z4;
      smp[0 * 272] = (ya0 + ya1) * 0.125f;   // k=000
      smp[1 * 272] = (ya0 - ya1) * 0.125f;   // 001
      smp[2 * 272] = (yd0 + yd1) * 0.125f;   // 010
      smp[3 * 272] = (yd0 - yd1) * 0.125f;   // 011
      smp[4 * 272] = (za0 + za1) * 0.125f;   // 100
      smp[5 * 272] = (za0 - za1) * 0.125f;   // 101
      smp[6 * 272] = (zd0 + zd1) * 0.125f;   // 110
      smp[7 * 272] = (zd0 - zd1) * 0.125f;   // 111
    }
  }
  __syncthreads();
  if (tid < 128u) {  // z-DFT: thread = (k, ny)
    unsigned k = tid >> 4, y = tid & 15u;
    const float* row = sm + k * 272u + y * 17u;
#pragma unroll
    for (int kz = 0; kz < 3; kz++) {
      float re = 0.f, im = 0.f;
#pragma unroll
      for (int nz = 0; nz < 16; nz++) {
        float vv = row[nz];
        int t16 = (kz * nz) & 15;
        re += vv * C16c[t16];
        im -= vv * S16c[t16];
      }
      fz[k * 51u + kz * 17u + y] = make_float2(re, im);
    }
  }
  __syncthreads();
  if (tid < 144u) {  // y-DFT -> g2[b][row][px][c]
    unsigned k = tid / 18u, r = tid - k * 18u;
    unsigned kyi = r / 3u, kz = r - kyi * 3u;
    int ky = KYv[kyi];
    float re = 0.f, im = 0.f;
#pragma unroll
    for (int ny = 0; ny < 16; ny++) {
      float2 vv = fz[k * 51u + kz * 17u + ny];
      int t16 = (ky * ny) & 15;
      float cc = C16c[t16], sn = S16c[t16];
      re += vv.x * cc + vv.y * sn;
      im += vv.y * cc - vv.x * sn;
    }
    g2[(((size_t)b * 144u + tid) * 16u + px) * 64u + c] = make_float2(re, im);
  }
}

// ---------------------------------------------------------------------------
// K2: x-DFT (in-LDS, per-corner) + channel mix reading w directly.
// WG = (kc = k*4+corner, ob in 8).  Prologue: thread (b,c) computes the 27
// corner-freqs of ih[b][c] -> LDS.  Main: thread (o,f) accumulates over i
// with NT w loads (8o x 27f = 1728B contiguous per i).
__global__ __launch_bounds__(256) void k2_mix(const float* __restrict__ w2,
                                              const float2* __restrict__ g2,
                                              float2* __restrict__ oh2) {
  __shared__ float2 ihl[4][64][27];   // [b][i=c][f]  55296 B
  unsigned tid = threadIdx.x;
  unsigned kc = blockIdx.x >> 3;
  unsigned ob = blockIdx.x & 7u;
  unsigned k = kc >> 2, corner = kc & 3u;
  unsigned kxi0 = 3u * (corner & 1u), kyi0 = 3u * (corner >> 1);
  {  // prologue: thread = (b, c)
    unsigned c = tid & 63u, b = tid >> 6;
    const float2* gb = g2 + ((size_t)b * 144u * 16u) * 64u + c;
#pragma unroll
    for (unsigned kyl = 0; kyl < 3u; kyl++) {
#pragma unroll
      for (unsigned kz = 0; kz < 3u; kz++) {
        unsigned row = k * 18u + (kyl + kyi0) * 3u + kz;
        float2 rg[16];
#pragma unroll
        for (int nx = 0; nx < 16; nx++) rg[nx] = gb[((size_t)row * 16u + nx) * 64u];
#pragma unroll
        for (unsigned kxl = 0; kxl < 3u; kxl++) {
          int kx = KYv[kxl + kxi0];
          float re = 0.f, im = 0.f;
#pragma unroll
          for (int nx = 0; nx < 16; nx++) {
            int t16 = (kx * nx) & 15;
            float cc = C16c[t16], sn = S16c[t16];
            re += rg[nx].x * cc + rg[nx].y * sn;
            im += rg[nx].y * cc - rg[nx].x * sn;
          }
          ihl[b][c][kxl * 9u + kyl * 3u + kz] = make_float2(re, im);
        }
      }
    }
  }
  __syncthreads();
  if (tid >= 216u) return;
  unsigned o = tid / 27u, f = tid - o * 27u;  // o in [0,8), f in [0,27)
  // w2 float layout: [kc][i][o64][f27][2]
  const float* wp = w2 + (((size_t)kc * 64u * 64u + (ob * 8u + o)) * 27u + f) * 2u;
  float2 acc[4];
#pragma unroll
  for (int b = 0; b < 4; b++) acc[b] = make_float2(0.f, 0.f);
#pragma unroll 8
  for (unsigned i = 0; i < 64u; i++) {
    float wr = __builtin_nontemporal_load(wp + (size_t)i * 3456u);
    float wi = __builtin_nontemporal_load(wp + (size_t)i * 3456u + 1u);
#pragma unroll
    for (int b = 0; b < 4; b++) {
      float2 a = ihl[b][i][f];
      acc[b].x += a.x * wr - a.y * wi;
      acc[b].y += a.x * wi + a.y * wr;
    }
  }
  unsigned kxl = f / 9u, kyl = (f - kxl * 9u) / 3u, kz = f % 3u;
  unsigned fg = (kxl + kxi0) * 18u + (kyl + kyi0) * 3u + kz;
#pragma unroll
  for (int b = 0; b < 4; b++)
    oh2[((size_t)(b * 64u + ob * 8u + o)) * 864u + k * 108u + fg] = acc[b];
}

// ---------------------------------------------------------------------------
// K3: fused inverse sparse DFT + synthesis. WG = (bo reversed, slab-pair).
// Normal x loads (LLC reuse of K1 tail); NT out stores.
__global__ __launch_bounds__(256) void k3_invsynth(const float2* __restrict__ oh2,
                                                   const float* __restrict__ x,
                                                   float* __restrict__ out) {
  __shared__ float2 hh[864];          // [k][fg]
  __shared__ float2 gx[2][8][18];     // [sl][k][kyi*3+kz]
  __shared__ float2 uu[2][8][3][16];  // [sl][k][kz][ny]
  __shared__ float W[2][8][16][16];   // [sl][m][ny][nz]
  unsigned tid = threadIdx.x;
  unsigned sp = blockIdx.x & 7u;              // slab pair: nx = sp*2 + sl
  unsigned bo = 255u - (blockIdx.x >> 3);     // reversed for LLC locality
  for (unsigned i = tid; i < 864u; i += 256u)
    hh[i] = oh2[(size_t)bo * 864u + i];
  __syncthreads();
  for (unsigned i = tid; i < 288u; i += 256u) {  // x-inverse (both slabs)
    unsigned sl = i / 144u, j = i - sl * 144u;
    unsigned k = j / 18u, r = j - k * 18u;
    unsigned nx = sp * 2u + sl;
    float re = 0.f, im = 0.f;
#pragma unroll
    for (int kxi = 0; kxi < 6; kxi++) {
      float2 v = hh[k * 108u + kxi * 18 + r];
      int t16 = (KYv[kxi] * (int)nx) & 15;
      float cc = C16c[t16], sn = S16c[t16];
      re += v.x * cc - v.y * sn;
      im += v.x * sn + v.y * cc;
    }
    gx[sl][k][r] = make_float2(re, im);
  }
  __syncthreads();
  for (unsigned i = tid; i < 768u; i += 256u) {  // y-inverse
    unsigned sl = i / 384u, j = i - sl * 384u;
    unsigned k = j / 48u, rem = j - k * 48u;
    unsigned kz = rem >> 4, ny = rem & 15u;
    float re = 0.f, im = 0.f;
#pragma unroll
    for (int kyi = 0; kyi < 6; kyi++) {
      float2 v = gx[sl][k][kyi * 3 + kz];
      int t16 = (KYv[kyi] * (int)ny) & 15;
      float cc = C16c[t16], sn = S16c[t16];
      re += v.x * cc - v.y * sn;
      im += v.x * sn + v.y * cc;
    }
    uu[sl][k][kz][ny] = make_float2(re, im);
  }
  __syncthreads();
  for (unsigned i = tid; i < 512u; i += 256u) {  // z-inverse + Hadamard
    unsigned sl = i >> 8, ny = (i >> 4) & 15u, nz = i & 15u;
    float c1 = C16c[nz], s1 = S16c[nz];
    int t2 = (2 * nz) & 15;
    float c2 = C16c[t2], s2 = S16c[t2];
    float val[8];
#pragma unroll
    for (int k = 0; k < 8; k++) {
      float2 u0 = uu[sl][k][0][ny], u1 = uu[sl][k][1][ny], u2 = uu[sl][k][2][ny];
      val[k] = (u0.x + 2.f * (u1.x * c1 - u1.y * s1) + 2.f * (u2.x * c2 - u2.y * s2)) * (1.f / 4096.f);
    }
#pragma unroll
    for (int st = 1; st < 8; st <<= 1)
#pragma unroll
      for (int i2 = 0; i2 < 8; i2++)
        if (!(i2 & st)) {
          float a = val[i2], bb = val[i2 | st];
          val[i2] = a + bb;
          val[i2 | st] = a - bb;
        }
#pragma unroll
    for (int m = 0; m < 8; m++) W[sl][m][ny][nz] = val[m];
  }
  __syncthreads();
  unsigned w = tid >> 6, l = tid & 63u;
  unsigned z4 = l & 15u, y2 = l >> 4;
  unsigned mmy = ((y2 >> 1) & 1u) << 1;
  const float* xp = x + ((size_t)bo << 18);
  float* op = out + ((size_t)bo << 18);
#pragma unroll
  for (unsigned sl = 0; sl < 2u; ++sl) {
#pragma unroll
    for (unsigned r2 = 0; r2 < 8u; ++r2) {
      unsigned xp2 = r2 & 1u, yg = r2 >> 1;
      unsigned X0 = ((sp * 2u + sl) << 2) + (xp2 << 1);
      unsigned Y = (yg << 4) + (w << 2) + y2;
      size_t off = ((size_t)X0 << 12) + (Y << 6) + (z4 << 2);
      f32x4 v0 = *(const f32x4*)(xp + off);
      f32x4 v1 = *(const f32x4*)(xp + off + 4096u);
      float h0 = v0.x + v0.y + v1.x + v1.y;
      float h1 = v0.z + v0.w + v1.z + v1.w;
      float m0 = (h0 + __shfl_xor(h0, 16)) * 0.125f;
      float m1 = (h1 + __shfl_xor(h1, 16)) * 0.125f;
      unsigned ny = (yg << 2) + w;
      unsigned mm = (xp2 << 2) | mmy;
      float c0 = 0.125f * W[sl][mm][ny][z4] - m0;
      float c1 = 0.125f * W[sl][mm | 1u][ny][z4] - m1;
      v0.x += c0; v0.y += c0; v0.z += c1; v0.w += c1;
      v1.x += c0; v1.y += c0; v1.z += c1; v1.w += c1;
      __builtin_nontemporal_store(v0, (f32x4*)(op + off));
      __builtin_nontemporal_store(v1, (f32x4*)(op + off + 4096u));
    }
  }
}

extern "C" void kernel_launch(void* const* d_in, const int* in_sizes, int n_in,
                              void* d_out, int out_size, void* d_ws, size_t ws_size,
                              hipStream_t stream) {
  const float* x = (const float*)d_in[0];
  const float* w = (const float*)d_in[1];
  float* out = (float*)d_out;

  const size_t G_B = 4ull * 144 * 16 * 64 * 8;   // 4.72 MB
  const size_t OH_B = 256ull * 864 * 8;          // 1.77 MB

  float2 *g2, *oh2;
  char* ws = (char*)d_ws;
  if (ws_size >= G_B + OH_B) {
    g2 = (float2*)ws;
    oh2 = (float2*)(ws + G_B);
  } else {
    // oh2 must survive into K3 -> ws (1.77 MB). g2 is dead after K2; park it
    // at the tail of d_out (K3 overwrites it only after K2 completed).
    oh2 = (float2*)ws;
    g2 = (float2*)((char*)d_out + (size_t)out_size * 4 - G_B);
  }

  k1_front<<<4096, 256, 0, stream>>>(x, g2);
  k2_mix<<<256, 256, 0, stream>>>(w, g2, oh2);
  k3_invsynth<<<2048, 256, 0, stream>>>(oh2, x, out);
}